// Round 22
// baseline (112.716 us; speedup 1.0000x reference)
//
#include <hip/hip_runtime.h>
#include <hip/hip_bf16.h>

#define K_DIM 256
#define OD 128
#define BSH 6                 // 64 rows per bucket
#define BROWS 64
#define BCAP 4096             // entries per bucket region (mean 2046, sd ~45)
#define FILL_THREADS 1024
#define FILL_CHUNK 8192       // 8 edges per thread
#define NB_MAX 1024

typedef __attribute__((ext_vector_type(8))) short short8;
typedef __attribute__((ext_vector_type(4))) float f32x4;

// pair bf16 convert (RNE) -> packed u32; compiler emits v_cvt_pk_bf16_f32
__device__ inline unsigned pack_bf2(float lo, float hi) {
    __hip_bfloat162 h = __float22bfloat162_rn(make_float2(lo, hi));
    return *reinterpret_cast<unsigned*>(&h);
}

__device__ inline unsigned short f2bf(float f) {
    unsigned u = __float_as_uint(f);
    unsigned r = (u + 0x7fffu + ((u >> 16) & 1u)) >> 16;   // round-to-nearest-even
    return (unsigned short)r;
}

union Frag8 { short8 s; uint4 u; };

// ---------------- init: pack W -> bf16 MFMA B-frag-linear, + bucket cursors ----------------
__global__ __launch_bounds__(256) void init_pack(const float* __restrict__ W,
                                                 uint4* __restrict__ wb,
                                                 int* __restrict__ gcur, int NB) {
    if ((int)blockIdx.x == 16) {           // bucket cursor init (padded: one per 64B line)
        for (int i = threadIdx.x; i < NB; i += 256) gcur[i * 16] = i * BCAP;
        return;
    }
    int t = blockIdx.x * 256 + threadIdx.x;
    if (t >= 8 * 8 * 64) return;
    int l  = t & 63;
    int n  = (t >> 6) & 7;
    int ks = t >> 9;
    int g  = l >> 4;
    int col = 16 * n + (l & 15);
    int kb  = 32 * ks + 4 * g;
    float e[8];
    #pragma unroll
    for (int j = 0; j < 8; ++j) {
        int k = kb + (j & 3) + 16 * (j >> 2);
        e[j] = W[(size_t)k * OD + col];
    }
    uint4 u;
    u.x = pack_bf2(e[0], e[1]);
    u.y = pack_bf2(e[2], e[3]);
    u.z = pack_bf2(e[4], e[5]);
    u.w = pack_bf2(e[6], e[7]);
    wb[t] = u;
}

// ---------------- MFMA GEMM: prebp = packed bf16(x @ W), 256 thr, no LDS, no syncs ----------------
// All 16 x-loads hoisted upfront (independent HBM misses in flight), then convert+MFMA.
// prebp[row*64 + w] = bf16(col w) | bf16(col w+64)<<16
__global__ __launch_bounds__(256) void gemm_mfma(const float* __restrict__ x,
                                                 const uint4* __restrict__ wb,
                                                 unsigned* __restrict__ prebp, int M) {
    const int t = threadIdx.x;
    const int l = t & 63;
    const int w = t >> 6;
    const int g = l >> 4;
    const int row  = blockIdx.x * 64 + w * 16 + (l & 15);
    const int rowc = row < M ? row : M - 1;
    const float* xp = x + (size_t)rowc * K_DIM + g * 4;

    // upfront: the whole K-strip for this (row, g) = 16 independent float4 loads
    float4 xr[16];
    #pragma unroll
    for (int i = 0; i < 16; ++i)
        xr[i] = *reinterpret_cast<const float4*>(xp + 16 * i);

    f32x4 acc[8];
    #pragma unroll
    for (int n = 0; n < 8; ++n) acc[n] = (f32x4){0.f, 0.f, 0.f, 0.f};

    #pragma unroll
    for (int ks = 0; ks < 8; ++ks) {
        Frag8 a;
        a.u.x = pack_bf2(xr[2 * ks].x,     xr[2 * ks].y);
        a.u.y = pack_bf2(xr[2 * ks].z,     xr[2 * ks].w);
        a.u.z = pack_bf2(xr[2 * ks + 1].x, xr[2 * ks + 1].y);
        a.u.w = pack_bf2(xr[2 * ks + 1].z, xr[2 * ks + 1].w);
        const uint4* wp = wb + (size_t)ks * 8 * 64 + l;
        #pragma unroll
        for (int n = 0; n < 8; ++n) {
            Frag8 bfrag;
            bfrag.u = wp[n * 64];
            acc[n] = __builtin_amdgcn_mfma_f32_16x16x32_bf16(a.s, bfrag.s, acc[n], 0, 0, 0);
        }
    }
    const int rbase = blockIdx.x * 64 + w * 16 + g * 4;
    #pragma unroll
    for (int r = 0; r < 4; ++r) {
        int ro = rbase + r;
        if (ro < M) {
            unsigned* dst = prebp + (size_t)ro * 64 + (l & 15);
            #pragma unroll
            for (int m = 0; m < 4; ++m)
                dst[16 * m] = pack_bf2(acc[m][r], acc[m + 4][r]);
        }
    }
}

// ---------------- fill: bucket-grouped compact edge stream (u32 entry + u8 row) ----------------
// 1024 threads, 8 edges/thread in registers, rank captured from count atomic.
// entry = col<<16 | bf16(val); row byte separate. Bucket b region: csr32/crow[b*BCAP ...).
__global__ __launch_bounds__(1024) void fill_bucket(const int* __restrict__ rows,
                                                    const int* __restrict__ cols,
                                                    const float* __restrict__ vals,
                                                    int* __restrict__ gcur,
                                                    unsigned* __restrict__ csr32,
                                                    unsigned char* __restrict__ crow,
                                                    int E, int NB) {
    __shared__ int cnt[NB_MAX];
    __shared__ int base[NB_MAX];
    const int t  = threadIdx.x;
    const int e0 = blockIdx.x * FILL_CHUNK;
    for (int i = t; i < NB; i += FILL_THREADS) cnt[i] = 0;
    __syncthreads();
    int r[8]; int c[8]; float v[8]; int rank[8];
    #pragma unroll
    for (int it = 0; it < 8; ++it) {
        int i = e0 + it * FILL_THREADS + t;
        if (i < E) {
            r[it]    = rows[i];
            c[it]    = cols[i];
            v[it]    = vals[i];
            rank[it] = atomicAdd(&cnt[r[it] >> BSH], 1);   // count AND capture rank
        } else r[it] = -1;
    }
    __syncthreads();
    for (int bkt = t; bkt < NB; bkt += FILL_THREADS) {
        int cn = cnt[bkt];
        base[bkt] = cn ? atomicAdd(&gcur[bkt * 16], cn) : 0;   // reserve contiguous run
    }
    __syncthreads();
    #pragma unroll
    for (int it = 0; it < 8; ++it) {
        if (r[it] >= 0) {
            int pos = base[r[it] >> BSH] + rank[it];            // no atomic here
            csr32[pos] = ((unsigned)c[it] << 16) | (unsigned)f2bf(v[it]);
            crow[pos]  = (unsigned char)(r[it] & (BROWS - 1));
        }
    }
}

// ---------------- gather: 512 thr/bucket (64 rows); compact sort (16KB sbuf); reg accumulation ----------------
// Wave w gathers rows {w, w+8, ..., w+56}; lane l owns cols {l, l+64}.
__global__ __launch_bounds__(512) void gather_sort(const int* __restrict__ gcur,
                                                   const unsigned* __restrict__ csr32,
                                                   const unsigned char* __restrict__ crow,
                                                   const unsigned* __restrict__ prebp,
                                                   const float* __restrict__ b,
                                                   float* __restrict__ out, int M) {
    __shared__ unsigned sbuf[BCAP];       // row-sorted entries, 16 KB
    __shared__ int cnt[BROWS];
    __shared__ int beg[BROWS];
    const int t   = threadIdx.x;
    const int bkt = (int)blockIdx.x;
    int nE = gcur[bkt * 16] - bkt * BCAP;
    nE = nE < BCAP ? nE : BCAP;
    const unsigned*      ce = csr32 + (size_t)bkt * BCAP;
    const unsigned char* re = crow  + (size_t)bkt * BCAP;

    if (t < BROWS) cnt[t] = 0;
    __syncthreads();
    // pass 1: register-stage entries + rows, capturing rank from the count atomic
    unsigned er[8]; int rw[8], rk[8];
    #pragma unroll
    for (int k = 0; k < 8; ++k) {
        int i = t + k * 512;
        if (i < nE) {
            er[k] = ce[i];
            rw[k] = (int)re[i];
            rk[k] = atomicAdd(&cnt[rw[k]], 1);
        } else rw[k] = -1;
    }
    __syncthreads();
    // exclusive scan of 64 counts in wave 0
    if (t < 64) {
        int c  = cnt[t];
        int sc = c;
        #pragma unroll
        for (int o = 1; o < 64; o <<= 1) {
            int u = __shfl_up(sc, o, 64);
            if (t >= o) sc += u;
        }
        beg[t] = sc - c;
    }
    __syncthreads();
    // pass 2: scatter regs into row-sorted LDS buffer (atomic-free: beg + rank)
    #pragma unroll
    for (int k = 0; k < 8; ++k) {
        if (rw[k] >= 0) sbuf[beg[rw[k]] + rk[k]] = er[k];
    }
    __syncthreads();

    // per-wave register gather over 8 rows (stride 8)
    const int l = t & 63, w = t >> 6;
    const float bv0 = b[l], bv1 = b[64 + l];
    const unsigned* pl = prebp + l;
    #pragma unroll 1
    for (int q = 0; q < 8; ++q) {
        int rr = w + 8 * q;
        int r  = (bkt << BSH) + rr;
        if (r >= M) continue;
        int j  = beg[rr];
        int je = j + cnt[rr];
        float a0 = 0.f, a1 = 0.f;
        for (; j + 7 < je; j += 8) {                     // 8 independent chains
            unsigned e0 = sbuf[j],     e1 = sbuf[j + 1], e2 = sbuf[j + 2], e3 = sbuf[j + 3];
            unsigned e4 = sbuf[j + 4], e5 = sbuf[j + 5], e6 = sbuf[j + 6], e7 = sbuf[j + 7];
            unsigned p0 = pl[(size_t)(e0 >> 16) * 64];
            unsigned p1 = pl[(size_t)(e1 >> 16) * 64];
            unsigned p2 = pl[(size_t)(e2 >> 16) * 64];
            unsigned p3 = pl[(size_t)(e3 >> 16) * 64];
            unsigned p4 = pl[(size_t)(e4 >> 16) * 64];
            unsigned p5 = pl[(size_t)(e5 >> 16) * 64];
            unsigned p6 = pl[(size_t)(e6 >> 16) * 64];
            unsigned p7 = pl[(size_t)(e7 >> 16) * 64];
            float v0 = __uint_as_float(e0 << 16), v1 = __uint_as_float(e1 << 16);
            float v2 = __uint_as_float(e2 << 16), v3 = __uint_as_float(e3 << 16);
            float v4 = __uint_as_float(e4 << 16), v5 = __uint_as_float(e5 << 16);
            float v6 = __uint_as_float(e6 << 16), v7 = __uint_as_float(e7 << 16);
            a0 = fmaf(v0, __uint_as_float(p0 << 16), a0);
            a1 = fmaf(v0, __uint_as_float(p0 & 0xffff0000u), a1);
            a0 = fmaf(v1, __uint_as_float(p1 << 16), a0);
            a1 = fmaf(v1, __uint_as_float(p1 & 0xffff0000u), a1);
            a0 = fmaf(v2, __uint_as_float(p2 << 16), a0);
            a1 = fmaf(v2, __uint_as_float(p2 & 0xffff0000u), a1);
            a0 = fmaf(v3, __uint_as_float(p3 << 16), a0);
            a1 = fmaf(v3, __uint_as_float(p3 & 0xffff0000u), a1);
            a0 = fmaf(v4, __uint_as_float(p4 << 16), a0);
            a1 = fmaf(v4, __uint_as_float(p4 & 0xffff0000u), a1);
            a0 = fmaf(v5, __uint_as_float(p5 << 16), a0);
            a1 = fmaf(v5, __uint_as_float(p5 & 0xffff0000u), a1);
            a0 = fmaf(v6, __uint_as_float(p6 << 16), a0);
            a1 = fmaf(v6, __uint_as_float(p6 & 0xffff0000u), a1);
            a0 = fmaf(v7, __uint_as_float(p7 << 16), a0);
            a1 = fmaf(v7, __uint_as_float(p7 & 0xffff0000u), a1);
        }
        for (; j < je; ++j) {
            unsigned e = sbuf[j];
            unsigned p = pl[(size_t)(e >> 16) * 64];
            float v = __uint_as_float(e << 16);
            a0 = fmaf(v, __uint_as_float(p << 16), a0);
            a1 = fmaf(v, __uint_as_float(p & 0xffff0000u), a1);
        }
        out[(size_t)r * OD + l]      = fmaxf(a0 + bv0, 0.f);
        out[(size_t)r * OD + 64 + l] = fmaxf(a1 + bv1, 0.f);
    }
}

// ---------------- fallback (tiny ws): atomic scatter over packed bf16 pre ----------------
__global__ __launch_bounds__(256) void spmm_scatter(const int* __restrict__ rows,
                                                    const int* __restrict__ cols,
                                                    const float* __restrict__ vals,
                                                    const unsigned* __restrict__ prebp,
                                                    float* __restrict__ out, int E) {
    const int e    = (int)((blockIdx.x * 256u + threadIdx.x) >> 6);
    const int lane = threadIdx.x & 63;
    if (e >= E) return;
    const int   r = rows[e];
    const int   c = cols[e];
    const float v = vals[e];
    unsigned p = prebp[(size_t)c * 64 + lane];
    float* o = out + (size_t)r * OD;
    unsafeAtomicAdd(o + lane,      v * __uint_as_float(p << 16));
    unsafeAtomicAdd(o + lane + 64, v * __uint_as_float(p & 0xffff0000u));
}

__global__ __launch_bounds__(256) void bias_relu(float* __restrict__ out,
                                                 const float* __restrict__ b, int n4) {
    int i = blockIdx.x * 256 + threadIdx.x;
    if (i >= n4) return;
    float4 v = reinterpret_cast<float4*>(out)[i];
    int c = (i & ((OD / 4) - 1)) << 2;
    float4 bv = *reinterpret_cast<const float4*>(b + c);
    v.x = fmaxf(v.x + bv.x, 0.f);
    v.y = fmaxf(v.y + bv.y, 0.f);
    v.z = fmaxf(v.z + bv.z, 0.f);
    v.w = fmaxf(v.w + bv.w, 0.f);
    reinterpret_cast<float4*>(out)[i] = v;
}

extern "C" void kernel_launch(void* const* d_in, const int* in_sizes, int n_in,
                              void* d_out, int out_size, void* d_ws, size_t ws_size,
                              hipStream_t stream) {
    const float* x     = (const float*)d_in[0];
    const int*   erows = (const int*)d_in[1];
    const int*   ecols = (const int*)d_in[2];
    const float* evals = (const float*)d_in[3];
    const float* W     = (const float*)d_in[4];
    const float* b     = (const float*)d_in[5];
    float*       out   = (float*)d_out;

    const int M  = in_sizes[0] / K_DIM;          // 50000 nodes
    const int E  = in_sizes[1];                  // 1.6M edges
    const int NB = (M + BROWS - 1) >> BSH;       // 782 buckets

    // workspace layout (16B-aligned)
    char* ws = (char*)d_ws;
    size_t off = 0;
    auto alloc = [&](size_t bytes) { char* p = ws + off; off = (off + bytes + 15) & ~(size_t)15; return p; };
    unsigned*      prebp = (unsigned*)alloc((size_t)M * 64 * sizeof(unsigned));    // 12.8 MB
    uint4*         wb    = (uint4*)alloc((size_t)8 * 8 * 64 * sizeof(uint4));      // 64 KB
    int*           gcur  = (int*)  alloc((size_t)NB * 16 * sizeof(int));           // padded cursors
    unsigned*      csr32 = (unsigned*)alloc((size_t)NB * BCAP * sizeof(unsigned)); // 12.8 MB
    unsigned char* crow  = (unsigned char*)alloc((size_t)NB * BCAP);               // 3.2 MB
    const bool bucket_ok = (off <= ws_size) && (NB <= NB_MAX) && (M <= 65536);

    const int nGemm = (M + 63) / 64;

    if (bucket_ok) {
        init_pack<<<17, 256, 0, stream>>>(W, wb, gcur, NB);
        gemm_mfma<<<nGemm, 256, 0, stream>>>(x, wb, prebp, M);
        fill_bucket<<<(E + FILL_CHUNK - 1) / FILL_CHUNK, FILL_THREADS, 0, stream>>>(
            erows, ecols, evals, gcur, csr32, crow, E, NB);
        gather_sort<<<NB, 512, 0, stream>>>(gcur, csr32, crow, prebp, b, out, M);
    } else {
        init_pack<<<16, 256, 0, stream>>>(W, wb, gcur, 0);
        gemm_mfma<<<nGemm, 256, 0, stream>>>(x, wb, prebp, M);
        hipMemsetAsync(d_out, 0, (size_t)out_size * sizeof(float), stream);
        spmm_scatter<<<(E + 3) / 4, 256, 0, stream>>>(erows, ecols, evals, prebp, out, E);
        bias_relu<<<(out_size / 4 + 255) / 256, 256, 0, stream>>>(out, b, out_size / 4);
    }
}

// Round 23
// 103.720 us; speedup vs baseline: 1.0867x; 1.0867x over previous
//
#include <hip/hip_runtime.h>
#include <hip/hip_bf16.h>

#define K_DIM 256
#define OD 128
#define BSH 6                 // 64 rows per bucket
#define BROWS 64
#define BCAP 4096             // entries per bucket region (mean 2046, sd ~45)
#define FILL_THREADS 1024
#define FILL_CHUNK 8192       // 8 edges per thread
#define NB_MAX 1024

typedef __attribute__((ext_vector_type(8))) short short8;
typedef __attribute__((ext_vector_type(4))) float f32x4;

// pair bf16 convert (RNE) -> packed u32; compiler emits v_cvt_pk_bf16_f32
__device__ inline unsigned pack_bf2(float lo, float hi) {
    __hip_bfloat162 h = __float22bfloat162_rn(make_float2(lo, hi));
    return *reinterpret_cast<unsigned*>(&h);
}

union Frag8 { short8 s; uint4 u; };

// ---------------- init: pack W -> bf16 MFMA B-frag-linear, + bucket cursors ----------------
__global__ __launch_bounds__(256) void init_pack(const float* __restrict__ W,
                                                 uint4* __restrict__ wb,
                                                 int* __restrict__ gcur, int NB) {
    if ((int)blockIdx.x == 16) {           // bucket cursor init (padded: one per 64B line)
        for (int i = threadIdx.x; i < NB; i += 256) gcur[i * 16] = i * BCAP;
        return;
    }
    int t = blockIdx.x * 256 + threadIdx.x;
    if (t >= 8 * 8 * 64) return;
    int l  = t & 63;
    int n  = (t >> 6) & 7;
    int ks = t >> 9;
    int g  = l >> 4;
    int col = 16 * n + (l & 15);
    int kb  = 32 * ks + 4 * g;
    float e[8];
    #pragma unroll
    for (int j = 0; j < 8; ++j) {
        int k = kb + (j & 3) + 16 * (j >> 2);
        e[j] = W[(size_t)k * OD + col];
    }
    uint4 u;
    u.x = pack_bf2(e[0], e[1]);
    u.y = pack_bf2(e[2], e[3]);
    u.z = pack_bf2(e[4], e[5]);
    u.w = pack_bf2(e[6], e[7]);
    wb[t] = u;
}

// ---------------- MFMA GEMM: prebp = packed bf16(x @ W), 256 thr, no LDS, no syncs ----------------
// All 16 x-loads hoisted upfront (independent HBM misses in flight), then convert+MFMA.
// prebp[row*64 + w] = bf16(col w) | bf16(col w+64)<<16
__global__ __launch_bounds__(256) void gemm_mfma(const float* __restrict__ x,
                                                 const uint4* __restrict__ wb,
                                                 unsigned* __restrict__ prebp, int M) {
    const int t = threadIdx.x;
    const int l = t & 63;
    const int w = t >> 6;
    const int g = l >> 4;
    const int row  = blockIdx.x * 64 + w * 16 + (l & 15);
    const int rowc = row < M ? row : M - 1;
    const float* xp = x + (size_t)rowc * K_DIM + g * 4;

    // upfront: the whole K-strip for this (row, g) = 16 independent float4 loads
    float4 xr[16];
    #pragma unroll
    for (int i = 0; i < 16; ++i)
        xr[i] = *reinterpret_cast<const float4*>(xp + 16 * i);

    f32x4 acc[8];
    #pragma unroll
    for (int n = 0; n < 8; ++n) acc[n] = (f32x4){0.f, 0.f, 0.f, 0.f};

    #pragma unroll
    for (int ks = 0; ks < 8; ++ks) {
        Frag8 a;
        a.u.x = pack_bf2(xr[2 * ks].x,     xr[2 * ks].y);
        a.u.y = pack_bf2(xr[2 * ks].z,     xr[2 * ks].w);
        a.u.z = pack_bf2(xr[2 * ks + 1].x, xr[2 * ks + 1].y);
        a.u.w = pack_bf2(xr[2 * ks + 1].z, xr[2 * ks + 1].w);
        const uint4* wp = wb + (size_t)ks * 8 * 64 + l;
        #pragma unroll
        for (int n = 0; n < 8; ++n) {
            Frag8 bfrag;
            bfrag.u = wp[n * 64];
            acc[n] = __builtin_amdgcn_mfma_f32_16x16x32_bf16(a.s, bfrag.s, acc[n], 0, 0, 0);
        }
    }
    const int rbase = blockIdx.x * 64 + w * 16 + g * 4;
    #pragma unroll
    for (int r = 0; r < 4; ++r) {
        int ro = rbase + r;
        if (ro < M) {
            unsigned* dst = prebp + (size_t)ro * 64 + (l & 15);
            #pragma unroll
            for (int m = 0; m < 4; ++m)
                dst[16 * m] = pack_bf2(acc[m][r], acc[m + 4][r]);
        }
    }
}

// ---------------- fill: bucket-grouped edge list, block-chunked reservation ----------------
// 1024 threads, 8 edges/thread in registers. Rank captured from the COUNT atomic.
// BROWS=64: NB-sweeps are 1 iteration, reserve atomics halved, runs ~21 edges (167B).
// entry.x = (row&63)<<16 | col, entry.y = val bits. Bucket b region: csr[b*BCAP ...).
__global__ __launch_bounds__(1024) void fill_bucket(const int* __restrict__ rows,
                                                    const int* __restrict__ cols,
                                                    const float* __restrict__ vals,
                                                    int* __restrict__ gcur,
                                                    uint2* __restrict__ csr, int E, int NB) {
    __shared__ int cnt[NB_MAX];
    __shared__ int base[NB_MAX];
    const int t  = threadIdx.x;
    const int e0 = blockIdx.x * FILL_CHUNK;
    for (int i = t; i < NB; i += FILL_THREADS) cnt[i] = 0;
    __syncthreads();
    int r[8]; int c[8]; float v[8]; int rank[8];
    #pragma unroll
    for (int it = 0; it < 8; ++it) {
        int i = e0 + it * FILL_THREADS + t;
        if (i < E) {
            r[it]    = rows[i];
            c[it]    = cols[i];
            v[it]    = vals[i];
            rank[it] = atomicAdd(&cnt[r[it] >> BSH], 1);   // count AND capture rank
        } else r[it] = -1;
    }
    __syncthreads();
    for (int bkt = t; bkt < NB; bkt += FILL_THREADS) {
        int cn = cnt[bkt];
        base[bkt] = cn ? atomicAdd(&gcur[bkt * 16], cn) : 0;   // reserve contiguous run
    }
    __syncthreads();
    #pragma unroll
    for (int it = 0; it < 8; ++it) {
        if (r[it] >= 0) {
            int pos = base[r[it] >> BSH] + rank[it];            // no atomic here
            csr[pos] = make_uint2(((unsigned)(r[it] & (BROWS - 1)) << 16) | (unsigned)c[it],
                                  __float_as_uint(v[it]));
        }
    }
}

// ---------------- gather: 512 thr/bucket (64 rows); reg-staged counting sort; reg accumulation ----------------
// 782 blocks -> all resident in ONE scheduling epoch (4 blocks/CU x 256 CU).
// Wave w gathers rows {w, w+8, ..., w+56}; lane l owns cols {l, l+64}.
__global__ __launch_bounds__(512) void gather_sort(const int* __restrict__ gcur,
                                                   const uint2* __restrict__ csr,
                                                   const unsigned* __restrict__ prebp,
                                                   const float* __restrict__ b,
                                                   float* __restrict__ out, int M) {
    __shared__ uint2 sbuf[BCAP];          // row-sorted entries, 32 KB
    __shared__ int cnt[BROWS];
    __shared__ int beg[BROWS];
    const int t   = threadIdx.x;
    const int bkt = (int)blockIdx.x;
    int nE = gcur[bkt * 16] - bkt * BCAP;
    nE = nE < BCAP ? nE : BCAP;
    const uint2* ep = csr + (size_t)bkt * BCAP;

    if (t < BROWS) cnt[t] = 0;
    __syncthreads();
    // pass 1: register-stage entries + count rows, capturing rank
    uint2 er[8]; int rk[8];
    #pragma unroll
    for (int k = 0; k < 8; ++k) {
        int i = t + k * 512;
        if (i < nE) {
            er[k] = ep[i];
            rk[k] = atomicAdd(&cnt[er[k].x >> 16], 1);
        } else er[k].x = 0xffffffffu;
    }
    __syncthreads();
    // exclusive scan of 64 counts in wave 0
    if (t < 64) {
        int c  = cnt[t];
        int sc = c;
        #pragma unroll
        for (int o = 1; o < 64; o <<= 1) {
            int u = __shfl_up(sc, o, 64);
            if (t >= o) sc += u;
        }
        beg[t] = sc - c;
    }
    __syncthreads();
    // pass 2: scatter regs into row-sorted LDS buffer (atomic-free: beg + rank)
    #pragma unroll
    for (int k = 0; k < 8; ++k) {
        if (er[k].x != 0xffffffffu) {
            int r = (int)(er[k].x >> 16);
            sbuf[beg[r] + rk[k]] = make_uint2(er[k].x & 0xffffu, er[k].y);
        }
    }
    __syncthreads();

    // per-wave register gather over 8 rows (stride 8)
    const int l = t & 63, w = t >> 6;
    const float bv0 = b[l], bv1 = b[64 + l];
    const unsigned* pl = prebp + l;
    #pragma unroll 1
    for (int q = 0; q < 8; ++q) {
        int rr = w + 8 * q;
        int r  = (bkt << BSH) + rr;
        if (r >= M) continue;
        int j  = beg[rr];
        int je = j + cnt[rr];
        float a0 = 0.f, a1 = 0.f;
        for (; j + 7 < je; j += 8) {                     // 8 independent chains
            uint2 e0 = sbuf[j],     e1 = sbuf[j + 1], e2 = sbuf[j + 2], e3 = sbuf[j + 3];
            uint2 e4 = sbuf[j + 4], e5 = sbuf[j + 5], e6 = sbuf[j + 6], e7 = sbuf[j + 7];
            unsigned p0 = pl[(size_t)e0.x * 64];
            unsigned p1 = pl[(size_t)e1.x * 64];
            unsigned p2 = pl[(size_t)e2.x * 64];
            unsigned p3 = pl[(size_t)e3.x * 64];
            unsigned p4 = pl[(size_t)e4.x * 64];
            unsigned p5 = pl[(size_t)e5.x * 64];
            unsigned p6 = pl[(size_t)e6.x * 64];
            unsigned p7 = pl[(size_t)e7.x * 64];
            float v0 = __uint_as_float(e0.y), v1 = __uint_as_float(e1.y);
            float v2 = __uint_as_float(e2.y), v3 = __uint_as_float(e3.y);
            float v4 = __uint_as_float(e4.y), v5 = __uint_as_float(e5.y);
            float v6 = __uint_as_float(e6.y), v7 = __uint_as_float(e7.y);
            a0 = fmaf(v0, __uint_as_float(p0 << 16), a0);
            a1 = fmaf(v0, __uint_as_float(p0 & 0xffff0000u), a1);
            a0 = fmaf(v1, __uint_as_float(p1 << 16), a0);
            a1 = fmaf(v1, __uint_as_float(p1 & 0xffff0000u), a1);
            a0 = fmaf(v2, __uint_as_float(p2 << 16), a0);
            a1 = fmaf(v2, __uint_as_float(p2 & 0xffff0000u), a1);
            a0 = fmaf(v3, __uint_as_float(p3 << 16), a0);
            a1 = fmaf(v3, __uint_as_float(p3 & 0xffff0000u), a1);
            a0 = fmaf(v4, __uint_as_float(p4 << 16), a0);
            a1 = fmaf(v4, __uint_as_float(p4 & 0xffff0000u), a1);
            a0 = fmaf(v5, __uint_as_float(p5 << 16), a0);
            a1 = fmaf(v5, __uint_as_float(p5 & 0xffff0000u), a1);
            a0 = fmaf(v6, __uint_as_float(p6 << 16), a0);
            a1 = fmaf(v6, __uint_as_float(p6 & 0xffff0000u), a1);
            a0 = fmaf(v7, __uint_as_float(p7 << 16), a0);
            a1 = fmaf(v7, __uint_as_float(p7 & 0xffff0000u), a1);
        }
        for (; j < je; ++j) {
            uint2 e = sbuf[j];
            unsigned p = pl[(size_t)e.x * 64];
            float v = __uint_as_float(e.y);
            a0 = fmaf(v, __uint_as_float(p << 16), a0);
            a1 = fmaf(v, __uint_as_float(p & 0xffff0000u), a1);
        }
        out[(size_t)r * OD + l]      = fmaxf(a0 + bv0, 0.f);
        out[(size_t)r * OD + 64 + l] = fmaxf(a1 + bv1, 0.f);
    }
}

// ---------------- fallback (tiny ws): atomic scatter over packed bf16 pre ----------------
__global__ __launch_bounds__(256) void spmm_scatter(const int* __restrict__ rows,
                                                    const int* __restrict__ cols,
                                                    const float* __restrict__ vals,
                                                    const unsigned* __restrict__ prebp,
                                                    float* __restrict__ out, int E) {
    const int e    = (int)((blockIdx.x * 256u + threadIdx.x) >> 6);
    const int lane = threadIdx.x & 63;
    if (e >= E) return;
    const int   r = rows[e];
    const int   c = cols[e];
    const float v = vals[e];
    unsigned p = prebp[(size_t)c * 64 + lane];
    float* o = out + (size_t)r * OD;
    unsafeAtomicAdd(o + lane,      v * __uint_as_float(p << 16));
    unsafeAtomicAdd(o + lane + 64, v * __uint_as_float(p & 0xffff0000u));
}

__global__ __launch_bounds__(256) void bias_relu(float* __restrict__ out,
                                                 const float* __restrict__ b, int n4) {
    int i = blockIdx.x * 256 + threadIdx.x;
    if (i >= n4) return;
    float4 v = reinterpret_cast<float4*>(out)[i];
    int c = (i & ((OD / 4) - 1)) << 2;
    float4 bv = *reinterpret_cast<const float4*>(b + c);
    v.x = fmaxf(v.x + bv.x, 0.f);
    v.y = fmaxf(v.y + bv.y, 0.f);
    v.z = fmaxf(v.z + bv.z, 0.f);
    v.w = fmaxf(v.w + bv.w, 0.f);
    reinterpret_cast<float4*>(out)[i] = v;
}

extern "C" void kernel_launch(void* const* d_in, const int* in_sizes, int n_in,
                              void* d_out, int out_size, void* d_ws, size_t ws_size,
                              hipStream_t stream) {
    const float* x     = (const float*)d_in[0];
    const int*   erows = (const int*)d_in[1];
    const int*   ecols = (const int*)d_in[2];
    const float* evals = (const float*)d_in[3];
    const float* W     = (const float*)d_in[4];
    const float* b     = (const float*)d_in[5];
    float*       out   = (float*)d_out;

    const int M  = in_sizes[0] / K_DIM;          // 50000 nodes
    const int E  = in_sizes[1];                  // 1.6M edges
    const int NB = (M + BROWS - 1) >> BSH;       // 782 buckets

    // workspace layout (16B-aligned)
    char* ws = (char*)d_ws;
    size_t off = 0;
    auto alloc = [&](size_t bytes) { char* p = ws + off; off = (off + bytes + 15) & ~(size_t)15; return p; };
    unsigned* prebp = (unsigned*)alloc((size_t)M * 64 * sizeof(unsigned));        // 12.8 MB
    uint4*    wb    = (uint4*)alloc((size_t)8 * 8 * 64 * sizeof(uint4));          // 64 KB
    int*      gcur  = (int*)  alloc((size_t)NB * 16 * sizeof(int));               // padded cursors
    uint2*    csr   = (uint2*)alloc((size_t)NB * BCAP * sizeof(uint2));           // 25.6 MB
    const bool bucket_ok = (off <= ws_size) && (NB <= NB_MAX) && (M <= 65536);

    const int nGemm = (M + 63) / 64;

    if (bucket_ok) {
        init_pack<<<17, 256, 0, stream>>>(W, wb, gcur, NB);
        gemm_mfma<<<nGemm, 256, 0, stream>>>(x, wb, prebp, M);
        fill_bucket<<<(E + FILL_CHUNK - 1) / FILL_CHUNK, FILL_THREADS, 0, stream>>>(
            erows, ecols, evals, gcur, csr, E, NB);
        gather_sort<<<NB, 512, 0, stream>>>(gcur, csr, prebp, b, out, M);
    } else {
        init_pack<<<16, 256, 0, stream>>>(W, wb, gcur, 0);
        gemm_mfma<<<nGemm, 256, 0, stream>>>(x, wb, prebp, M);
        hipMemsetAsync(d_out, 0, (size_t)out_size * sizeof(float), stream);
        spmm_scatter<<<(E + 3) / 4, 256, 0, stream>>>(erows, ecols, evals, prebp, out, E);
        bias_relu<<<(out_size / 4 + 255) / 256, 256, 0, stream>>>(out, b, out_size / 4);
    }
}